// Round 1
// baseline (4487.332 us; speedup 1.0000x reference)
//
#include <hip/hip_runtime.h>
#include <hip/hip_bf16.h>

#define T_SEQ 200
#define HDIM  256
#define EDIM  256
#define G3    768   // 3*H
#define TOUT  199   // T-1

// swizzled word index in h_lds for hidden element j (float4-block XOR swizzle)
__device__ __forceinline__ int swz(int j) {
  int blk = j >> 2;            // 64 float4 blocks
  int pos = blk ^ (blk >> 3);  // spread 128B-strided readers across banks
  return (pos << 2) | (j & 3);
}

// ---------------------------------------------------------------------------
// Kernel A: gi[m][g] = sum_e (q_emb[q[m]][e] + a_emb[a[m]][e]) * w_ih[g][e] + b_ih[g]
// M=12800, N=768, K=256.  Grid (100, 6), block 256, 128x128 tile, 8x8 microtile.
// No LDS: w_ih (768KB) and gathered q_emb rows are L2-resident and broadcast-read.
// ---------------------------------------------------------------------------
__global__ __launch_bounds__(256) void gi_gemm_kernel(
    const int* __restrict__ questions,
    const int* __restrict__ answers,
    const float* __restrict__ q_emb,
    const float* __restrict__ a_emb,
    const float* __restrict__ w_ih,
    const float* __restrict__ b_ih,
    float* __restrict__ gi)
{
  const int tx = threadIdx.x & 15;
  const int ty = threadIdx.x >> 4;
  const int m0 = blockIdx.x * 128 + ty * 8;
  const int n0 = blockIdx.y * 128 + tx * 8;

  const float* qb[8];
  const float* ab[8];
  const float* wb[8];
#pragma unroll
  for (int i = 0; i < 8; ++i) {
    int q = questions[m0 + i]; q = q < 0 ? 0 : q;
    int a = answers[m0 + i];   a = a < 0 ? 0 : a;
    qb[i] = q_emb + (size_t)q * EDIM;
    ab[i] = a_emb + (size_t)a * EDIM;
    wb[i] = w_ih + (size_t)(n0 + i) * EDIM;
  }

  float acc[8][8] = {};
  for (int k = 0; k < EDIM; k += 4) {
    float4 av[8], bv[8];
#pragma unroll
    for (int i = 0; i < 8; ++i) {
      float4 qv = *(const float4*)(qb[i] + k);
      float4 ev = *(const float4*)(ab[i] + k);
      av[i] = make_float4(qv.x + ev.x, qv.y + ev.y, qv.z + ev.z, qv.w + ev.w);
    }
#pragma unroll
    for (int jj = 0; jj < 8; ++jj) bv[jj] = *(const float4*)(wb[jj] + k);
#pragma unroll
    for (int i = 0; i < 8; ++i)
#pragma unroll
      for (int jj = 0; jj < 8; ++jj) {
        acc[i][jj] += av[i].x * bv[jj].x + av[i].y * bv[jj].y +
                      av[i].z * bv[jj].z + av[i].w * bv[jj].w;
      }
  }

  float bias[8];
#pragma unroll
  for (int jj = 0; jj < 8; ++jj) bias[jj] = b_ih[n0 + jj];

#pragma unroll
  for (int i = 0; i < 8; ++i) {
    float* dst = gi + (size_t)(m0 + i) * G3 + n0;
    float4 o0 = make_float4(acc[i][0] + bias[0], acc[i][1] + bias[1],
                            acc[i][2] + bias[2], acc[i][3] + bias[3]);
    float4 o1 = make_float4(acc[i][4] + bias[4], acc[i][5] + bias[5],
                            acc[i][6] + bias[6], acc[i][7] + bias[7]);
    *(float4*)dst = o0;
    *(float4*)(dst + 4) = o1;
  }
}

// ---------------------------------------------------------------------------
// Kernel B: sequential GRU scan. 64 blocks (one per batch element) x 1024 thr.
// W_hh register-resident: group g = tid>>3 owns rows {g,128+g,256+g,384+g,512+g,640+g},
// lane sub = tid&7 owns 32 contiguous K-elements of each row.
// ---------------------------------------------------------------------------
__global__ __launch_bounds__(1024) void gru_scan_kernel(
    const int* __restrict__ questions,
    const float* __restrict__ w_hh,    // [768][256]
    const float* __restrict__ b_hh,    // [768]
    const float* __restrict__ pred_w,  // [Q+1][256]
    const float* __restrict__ pred_b,  // [Q+1]
    const float* __restrict__ gi,      // [B*T][768]
    float* __restrict__ out)           // [B][199]
{
  const int b    = blockIdx.x;
  const int tid  = threadIdx.x;
  const int lane = tid & 63;
  const int wave = tid >> 6;
  const int g    = tid >> 3;  // 0..127
  const int sub  = tid & 7;   // 0..7

  __shared__ __align__(16) float h_lds[256];
  __shared__ float gi_buf[2][G3];

  // --- W_hh slice into registers: 6 rows x 8 float4 = 192 VGPRs ---
  float4 w4[6][8];
#pragma unroll
  for (int m = 0; m < 6; ++m) {
    const float* wp = w_hh + (size_t)(128 * m + g) * HDIM + sub * 32;
#pragma unroll
    for (int c = 0; c < 8; ++c) w4[m][c] = *(const float4*)(wp + 4 * c);
  }

  const bool gate = (sub < 2);
  const int j = g + (sub << 7);          // sub==0 -> g, sub==1 -> g+128
  float bh_r = 0.f, bh_z = 0.f, bh_n = 0.f;
  if (gate) {
    bh_r = b_hh[j];
    bh_z = b_hh[HDIM + j];
    bh_n = b_hh[2 * HDIM + j];
  }

  // --- init h = 0, stage gi row 0, prefetch pred row for t=0 ---
  if (tid < 256) h_lds[tid] = 0.0f;
  const float* gi_b = gi + (size_t)b * T_SEQ * G3;
  if (tid < G3) gi_buf[0][tid] = gi_b[tid];
  const int* q_b = questions + b * T_SEQ;

  float pw0 = 0.f, pw1 = 0.f, pw2 = 0.f, pw3 = 0.f, pbias = 0.f;
  if (wave == 0) {
    int q0 = q_b[0]; q0 = q0 < 0 ? 0 : q0;
    const float* pr = pred_w + (size_t)q0 * HDIM;
    pw0 = pr[lane];       pw1 = pr[lane + 64];
    pw2 = pr[lane + 128]; pw3 = pr[lane + 192];
    pbias = pred_b[q0];
  }
  __syncthreads();

  int cur = 0;
  for (int t = 0; t < TOUT; ++t) {
    // phase 0: issue prefetches for t+1 (latency hides under matvec)
    float gnext = 0.0f;
    if (tid < G3) gnext = gi_b[(size_t)(t + 1) * G3 + tid];
    float nw0 = 0.f, nw1 = 0.f, nw2 = 0.f, nw3 = 0.f, npb = 0.f;
    if (wave == 0) {
      int qn = q_b[t + 1]; qn = qn < 0 ? 0 : qn;
      const float* pr = pred_w + (size_t)qn * HDIM;
      nw0 = pr[lane];       nw1 = pr[lane + 64];
      nw2 = pr[lane + 128]; nw3 = pr[lane + 192];
      npb = pred_b[qn];
    }

    // phase 1: read h (swizzled, conflict-free float4 reads)
    float4 h4[8];
#pragma unroll
    for (int c = 0; c < 8; ++c) {
      int pblk = ((sub << 3) | c) ^ sub;
      h4[c] = *(const float4*)&h_lds[pblk << 2];
    }
    float hold = 0.0f;
    if (gate) hold = h_lds[swz(j)];
    __syncthreads();  // B1: all reads of h_t done before any overwrite

    // phase 2: matvec partials (192 FMA/thread)
    float acc[6];
#pragma unroll
    for (int m = 0; m < 6; ++m) {
      float s = 0.0f;
#pragma unroll
      for (int c = 0; c < 8; ++c) {
        float4 wv = w4[m][c];
        float4 hv = h4[c];
        s += wv.x * hv.x; s += wv.y * hv.y;
        s += wv.z * hv.z; s += wv.w * hv.w;
      }
      acc[m] = s;
    }
    // reduce across the 8 lanes of each group
#pragma unroll
    for (int m = 0; m < 6; ++m) {
      float s = acc[m];
      s += __shfl_xor(s, 1);
      s += __shfl_xor(s, 2);
      s += __shfl_xor(s, 4);
      acc[m] = s;
    }

    // gates: lane sub0 -> unit g, lane sub1 -> unit g+128
    if (gate) {
      float hr = (sub == 0) ? acc[0] : acc[1];
      float hz = (sub == 0) ? acc[2] : acc[3];
      float hn = (sub == 0) ? acc[4] : acc[5];
      float gr = gi_buf[cur][j];
      float gz = gi_buf[cur][HDIM + j];
      float gn = gi_buf[cur][2 * HDIM + j];
      float r = 1.0f / (1.0f + expf(-(gr + hr + bh_r)));
      float z = 1.0f / (1.0f + expf(-(gz + hz + bh_z)));
      float n = tanhf(gn + r * (hn + bh_n));
      float hnew = (1.0f - z) * n + z * hold;
      h_lds[swz(j)] = hnew;
    }
    if (tid < G3) gi_buf[cur ^ 1][tid] = gnext;
    __syncthreads();  // B2: h_{t+1} + next gi row visible

    // phase 3: prediction on wave 0 with prefetched pred row
    if (wave == 0) {
      float s = h_lds[swz(lane)]        * pw0
              + h_lds[swz(64 + lane)]   * pw1
              + h_lds[swz(128 + lane)]  * pw2
              + h_lds[swz(192 + lane)]  * pw3;
      s += __shfl_xor(s, 1);  s += __shfl_xor(s, 2);
      s += __shfl_xor(s, 4);  s += __shfl_xor(s, 8);
      s += __shfl_xor(s, 16); s += __shfl_xor(s, 32);
      if (lane == 0) out[b * TOUT + t] = 1.0f / (1.0f + expf(-(s + pbias)));
      pw0 = nw0; pw1 = nw1; pw2 = nw2; pw3 = nw3; pbias = npb;
    }
    cur ^= 1;
  }
}

// ---------------------------------------------------------------------------
extern "C" void kernel_launch(void* const* d_in, const int* in_sizes, int n_in,
                              void* d_out, int out_size, void* d_ws, size_t ws_size,
                              hipStream_t stream) {
  // setup_inputs order:
  // 0 features (unused), 1 questions, 2 answers, 3 q_emb, 4 a_emb,
  // 5 gru_w_ih, 6 gru_w_hh, 7 gru_b_ih, 8 gru_b_hh, 9 pred_w, 10 pred_b
  const int*   questions = (const int*)d_in[1];
  const int*   answers   = (const int*)d_in[2];
  const float* q_emb     = (const float*)d_in[3];
  const float* a_emb     = (const float*)d_in[4];
  const float* w_ih      = (const float*)d_in[5];
  const float* w_hh      = (const float*)d_in[6];
  const float* b_ih      = (const float*)d_in[7];
  const float* b_hh      = (const float*)d_in[8];
  const float* pred_w    = (const float*)d_in[9];
  const float* pred_b    = (const float*)d_in[10];
  float* out = (float*)d_out;

  float* gi = (float*)d_ws;  // [64*200][768] fp32 = 39.3 MB

  gi_gemm_kernel<<<dim3(100, 6), 256, 0, stream>>>(
      questions, answers, q_emb, a_emb, w_ih, b_ih, gi);

  gru_scan_kernel<<<64, 1024, 0, stream>>>(
      questions, w_hh, b_hh, pred_w, pred_b, gi, out);
}

// Round 2
// 600.089 us; speedup vs baseline: 7.4778x; 7.4778x over previous
//
#include <hip/hip_runtime.h>
#include <hip/hip_bf16.h>

#define T_SEQ 200
#define HDIM  256
#define EDIM  256
#define G3    768   // 3*H
#define TOUT  199   // T-1

typedef _Float16 h2_t __attribute__((ext_vector_type(2)));

static __device__ __forceinline__ float dot2acc(h2_t a, h2_t b, float c) {
#if __has_builtin(__builtin_amdgcn_fdot2)
  return __builtin_amdgcn_fdot2(a, b, c, false);
#else
  return c + (float)a[0] * (float)b[0] + (float)a[1] * (float)b[1];
#endif
}

// ---------------------------------------------------------------------------
// Kernel A: gi[m][g] = sum_e (q_emb[q[m]][e] + a_emb[a[m]][e]) * w_ih[g][e] + b_ih[g]
// M=12800, N=768, K=256.  Grid (100, 6), block 256, 128x128 tile, 8x8 microtile.
// ---------------------------------------------------------------------------
__global__ __launch_bounds__(256) void gi_gemm_kernel(
    const int* __restrict__ questions,
    const int* __restrict__ answers,
    const float* __restrict__ q_emb,
    const float* __restrict__ a_emb,
    const float* __restrict__ w_ih,
    const float* __restrict__ b_ih,
    float* __restrict__ gi)
{
  const int tx = threadIdx.x & 15;
  const int ty = threadIdx.x >> 4;
  const int m0 = blockIdx.x * 128 + ty * 8;
  const int n0 = blockIdx.y * 128 + tx * 8;

  const float* qb[8];
  const float* ab[8];
  const float* wb[8];
#pragma unroll
  for (int i = 0; i < 8; ++i) {
    int q = questions[m0 + i]; q = q < 0 ? 0 : q;
    int a = answers[m0 + i];   a = a < 0 ? 0 : a;
    qb[i] = q_emb + (size_t)q * EDIM;
    ab[i] = a_emb + (size_t)a * EDIM;
    wb[i] = w_ih + (size_t)(n0 + i) * EDIM;
  }

  float acc[8][8] = {};
  for (int k = 0; k < EDIM; k += 4) {
    float4 av[8], bv[8];
#pragma unroll
    for (int i = 0; i < 8; ++i) {
      float4 qv = *(const float4*)(qb[i] + k);
      float4 ev = *(const float4*)(ab[i] + k);
      av[i] = make_float4(qv.x + ev.x, qv.y + ev.y, qv.z + ev.z, qv.w + ev.w);
    }
#pragma unroll
    for (int jj = 0; jj < 8; ++jj) bv[jj] = *(const float4*)(wb[jj] + k);
#pragma unroll
    for (int i = 0; i < 8; ++i)
#pragma unroll
      for (int jj = 0; jj < 8; ++jj) {
        acc[i][jj] += av[i].x * bv[jj].x + av[i].y * bv[jj].y +
                      av[i].z * bv[jj].z + av[i].w * bv[jj].w;
      }
  }

  float bias[8];
#pragma unroll
  for (int jj = 0; jj < 8; ++jj) bias[jj] = b_ih[n0 + jj];

#pragma unroll
  for (int i = 0; i < 8; ++i) {
    float* dst = gi + (size_t)(m0 + i) * G3 + n0;
    float4 o0 = make_float4(acc[i][0] + bias[0], acc[i][1] + bias[1],
                            acc[i][2] + bias[2], acc[i][3] + bias[3]);
    float4 o1 = make_float4(acc[i][4] + bias[4], acc[i][5] + bias[5],
                            acc[i][6] + bias[6], acc[i][7] + bias[7]);
    *(float4*)dst = o0;
    *(float4*)(dst + 4) = o1;
  }
}

// ---------------------------------------------------------------------------
// Kernel B: sequential GRU scan. 64 blocks (one per batch element) x 512 thr.
// W_hh register-resident as packed fp16: thread (g=tid>>1, sub=tid&1) owns
// rows {g, 256+g, 512+g}, cols [sub*128, sub*128+128) -> 192 half2 VGPRs.
// h kept in LDS as fp32 (recurrence/pred) AND fp16 (dot2 matvec operand).
// ---------------------------------------------------------------------------
__global__ __launch_bounds__(512, 2) void gru_scan_kernel(
    const int* __restrict__ questions,
    const float* __restrict__ w_hh,    // [768][256]
    const float* __restrict__ b_hh,    // [768]
    const float* __restrict__ pred_w,  // [Q+1][256]
    const float* __restrict__ pred_b,  // [Q+1]
    const float* __restrict__ gi,      // [B*T][768]
    float* __restrict__ out)           // [B][199]
{
  const int b    = blockIdx.x;
  const int tid  = threadIdx.x;
  const int lane = tid & 63;
  const int g    = tid >> 1;   // hidden unit 0..255
  const int sub  = tid & 1;    // column half

  __shared__ __align__(16) float    hf[HDIM];     // fp32 h
  __shared__ __align__(16) _Float16 hh[HDIM];     // fp16 h (matvec operand)
  __shared__ float gi_buf[2][G3];

  // --- W_hh slice -> registers, fp16 packed: 3 rows x 64 half2 = 192 VGPRs ---
  h2_t w2[3][64];
#pragma unroll
  for (int m = 0; m < 3; ++m) {
    const float* wp = w_hh + (size_t)(m * HDIM + g) * HDIM + sub * 128;
#pragma unroll
    for (int c = 0; c < 32; ++c) {
      float4 f = *(const float4*)(wp + 4 * c);
      h2_t p0, p1;
      p0[0] = (_Float16)f.x; p0[1] = (_Float16)f.y;
      p1[0] = (_Float16)f.z; p1[1] = (_Float16)f.w;
      w2[m][2 * c]     = p0;
      w2[m][2 * c + 1] = p1;
    }
  }

  float bh_r = 0.f, bh_z = 0.f, bh_n = 0.f;
  if (sub == 0) {
    bh_r = b_hh[g];
    bh_z = b_hh[HDIM + g];
    bh_n = b_hh[2 * HDIM + g];
  }

  // --- init h = 0, stage gi row 0, prefetch pred row for t=0 ---
  if (tid < HDIM) { hf[tid] = 0.0f; hh[tid] = (_Float16)0.0f; }
  const float* gi_b = gi + (size_t)b * T_SEQ * G3;
  gi_buf[0][tid] = gi_b[tid];
  if (tid < G3 - 512) gi_buf[0][512 + tid] = gi_b[512 + tid];
  const int* q_b = questions + b * T_SEQ;

  float pw0 = 0.f, pw1 = 0.f, pw2 = 0.f, pw3 = 0.f, pbias = 0.f;
  if (tid < 64) {
    int q0 = q_b[0]; q0 = q0 < 0 ? 0 : q0;
    const float* pr = pred_w + (size_t)q0 * HDIM;
    pw0 = pr[lane];       pw1 = pr[lane + 64];
    pw2 = pr[lane + 128]; pw3 = pr[lane + 192];
    pbias = pred_b[q0];
  }
  __syncthreads();

  int cur = 0;
  for (int t = 0; t < TOUT; ++t) {
    // phase 0: issue prefetches for t+1 (latency hides under matvec)
    float gn0 = 0.0f, gn1 = 0.0f;
    gn0 = gi_b[(size_t)(t + 1) * G3 + tid];
    if (tid < G3 - 512) gn1 = gi_b[(size_t)(t + 1) * G3 + 512 + tid];
    float nw0 = 0.f, nw1 = 0.f, nw2 = 0.f, nw3 = 0.f, npb = 0.f;
    if (tid < 64) {
      int qn = q_b[t + 1]; qn = qn < 0 ? 0 : qn;
      const float* pr = pred_w + (size_t)qn * HDIM;
      nw0 = pr[lane];       nw1 = pr[lane + 64];
      nw2 = pr[lane + 128]; nw3 = pr[lane + 192];
      npb = pred_b[qn];
    }

    // phase 1: matvec over this thread's 128-col half (broadcast LDS reads)
    const _Float16* hp = hh + sub * 128;
    float acc[3][2] = {};
#pragma unroll
    for (int c = 0; c < 16; ++c) {
      float4 hraw = *(const float4*)(hp + 8 * c);
      const h2_t* hv = reinterpret_cast<const h2_t*>(&hraw);
#pragma unroll
      for (int m = 0; m < 3; ++m) {
#pragma unroll
        for (int j = 0; j < 4; ++j) {
          acc[m][j & 1] = dot2acc(w2[m][4 * c + j], hv[j], acc[m][j & 1]);
        }
      }
    }
    float hold = hf[g];  // read h_t before anyone overwrites
    float s_r = acc[0][0] + acc[0][1];
    float s_z = acc[1][0] + acc[1][1];
    float s_n = acc[2][0] + acc[2][1];
    // pair reduce: tid 2g (cols 0-127) + tid 2g+1 (cols 128-255)
    s_r += __shfl_xor(s_r, 1);
    s_z += __shfl_xor(s_z, 1);
    s_n += __shfl_xor(s_n, 1);
    __syncthreads();  // B1: all reads of h_t done before overwrite

    // phase 2: gates on sub==0, write h_{t+1}; stage next gi row
    if (sub == 0) {
      float gr = gi_buf[cur][g];
      float gz = gi_buf[cur][HDIM + g];
      float gn = gi_buf[cur][2 * HDIM + g];
      float r = 1.0f / (1.0f + expf(-(gr + s_r + bh_r)));
      float z = 1.0f / (1.0f + expf(-(gz + s_z + bh_z)));
      float n = tanhf(gn + r * (s_n + bh_n));
      float hnew = (1.0f - z) * n + z * hold;
      hf[g] = hnew;
      hh[g] = (_Float16)hnew;
    }
    gi_buf[cur ^ 1][tid] = gn0;
    if (tid < G3 - 512) gi_buf[cur ^ 1][512 + tid] = gn1;
    __syncthreads();  // B2: h_{t+1} + next gi row visible

    // phase 3: prediction on wave 0 with prefetched pred row
    if (tid < 64) {
      float s = hf[lane]       * pw0
              + hf[64 + lane]  * pw1
              + hf[128 + lane] * pw2
              + hf[192 + lane] * pw3;
      s += __shfl_xor(s, 1);  s += __shfl_xor(s, 2);
      s += __shfl_xor(s, 4);  s += __shfl_xor(s, 8);
      s += __shfl_xor(s, 16); s += __shfl_xor(s, 32);
      if (lane == 0) out[b * TOUT + t] = 1.0f / (1.0f + expf(-(s + pbias)));
      pw0 = nw0; pw1 = nw1; pw2 = nw2; pw3 = nw3; pbias = npb;
    }
    cur ^= 1;
  }
}

// ---------------------------------------------------------------------------
extern "C" void kernel_launch(void* const* d_in, const int* in_sizes, int n_in,
                              void* d_out, int out_size, void* d_ws, size_t ws_size,
                              hipStream_t stream) {
  const int*   questions = (const int*)d_in[1];
  const int*   answers   = (const int*)d_in[2];
  const float* q_emb     = (const float*)d_in[3];
  const float* a_emb     = (const float*)d_in[4];
  const float* w_ih      = (const float*)d_in[5];
  const float* w_hh      = (const float*)d_in[6];
  const float* b_ih      = (const float*)d_in[7];
  const float* b_hh      = (const float*)d_in[8];
  const float* pred_w    = (const float*)d_in[9];
  const float* pred_b    = (const float*)d_in[10];
  float* out = (float*)d_out;

  float* gi = (float*)d_ws;  // [64*200][768] fp32 = 39.3 MB

  gi_gemm_kernel<<<dim3(100, 6), 256, 0, stream>>>(
      questions, answers, q_emb, a_emb, w_ih, b_ih, gi);

  gru_scan_kernel<<<64, 512, 0, stream>>>(
      questions, w_hh, b_hh, pred_w, pred_b, gi, out);
}